// Round 1
// baseline (388.836 us; speedup 1.0000x reference)
//
#include <hip/hip_runtime.h>
#include <hip/hip_bf16.h>
#include <stdint.h>

// Problem constants (fixed by reference)
#define M_DIM 8192   // 4*2048
#define N_DIM 4096   // OUT_FEATURES
#define K_DIM 4096   // IN_FEATURES

typedef __attribute__((ext_vector_type(8))) __bf16 bf16x8;
typedef __attribute__((ext_vector_type(4))) float  f32x4;

// async global->LDS, 16B per lane (global_load_lds_dwordx4)
#define GLD_LDS16(gaddr, laddr)                                            \
  __builtin_amdgcn_global_load_lds(                                        \
      (const __attribute__((address_space(1))) uint32_t*)(gaddr),          \
      (__attribute__((address_space(3))) uint32_t*)(laddr), 16, 0, 0)

// ---------------------------------------------------------------------------
// Dequant: qweight (8, O, 128) int32 bit-planes + lut (O,16) -> Wb (O,K) bf16
// One thread per (o, w): 32 weights, 64B contiguous store.
// ---------------------------------------------------------------------------
__global__ __launch_bounds__(256) void anyprec_dequant_kernel(
    const int* __restrict__ q, const float* __restrict__ lut,
    __bf16* __restrict__ Wb) {
  int t = blockIdx.x * 256 + threadIdx.x;   // 0 .. O*128-1
  int o = t >> 7;
  int w = t & 127;
  const int PLANE = N_DIM * (K_DIM / 32);   // 4096*128
  int base = o * (K_DIM / 32) + w;
  uint32_t q0 = (uint32_t)q[0 * PLANE + base];
  uint32_t q1 = (uint32_t)q[1 * PLANE + base];
  uint32_t q2 = (uint32_t)q[2 * PLANE + base];
  uint32_t q3 = (uint32_t)q[3 * PLANE + base];
  const float* lrow = lut + o * 16;

  __bf16 vals[32];
#pragma unroll
  for (int i = 0; i < 32; ++i) {
    uint32_t idx = ((q0 >> i) & 1u) | (((q1 >> i) & 1u) << 1) |
                   (((q2 >> i) & 1u) << 2) | (((q3 >> i) & 1u) << 3);
    vals[i] = (__bf16)lrow[idx];   // L1-resident 64B line per o-row
  }
  bf16x8* dst = (bf16x8*)(Wb + (size_t)o * K_DIM + w * 32);
#pragma unroll
  for (int r = 0; r < 4; ++r) {
    bf16x8 v;
#pragma unroll
    for (int j = 0; j < 8; ++j) v[j] = vals[r * 8 + j];
    dst[r] = v;
  }
}

// ---------------------------------------------------------------------------
// x fp32 -> bf16, 8 elements / thread, vectorized
// ---------------------------------------------------------------------------
__global__ __launch_bounds__(256) void cvt_x_kernel(
    const float* __restrict__ x, __bf16* __restrict__ xb, int n8) {
  int t = blockIdx.x * 256 + threadIdx.x;
  if (t >= n8) return;
  f32x4 a = ((const f32x4*)x)[t * 2];
  f32x4 b = ((const f32x4*)x)[t * 2 + 1];
  bf16x8 v;
  v[0] = (__bf16)a[0]; v[1] = (__bf16)a[1]; v[2] = (__bf16)a[2]; v[3] = (__bf16)a[3];
  v[4] = (__bf16)b[0]; v[5] = (__bf16)b[1]; v[6] = (__bf16)b[2]; v[7] = (__bf16)b[3];
  ((bf16x8*)xb)[t] = v;
}

// ---------------------------------------------------------------------------
// GEMM: C[M,N] = A[M,K](bf16) * B[N,K](bf16)^T + bias, fp32 out
// m97 structure: 128x128 tile, BK=32, 4 waves (2x2), each wave 64x64 via
// 4x4 grid of 16x16x32 bf16 MFMA. global_load_lds width-16 staging.
// ---------------------------------------------------------------------------
__global__ __launch_bounds__(256, 2) void anyprec_gemm_kernel(
    const __bf16* __restrict__ A,   // M x K
    const __bf16* __restrict__ B,   // N x K (row o = output channel)
    const float* __restrict__ bias,
    float* __restrict__ C) {
  __shared__ __bf16 lsA[128 * 32];
  __shared__ __bf16 lsB[128 * 32];

  // XCD-aware bijective swizzle (nwg = 2048, divisible by 8)
  int bid = blockIdx.x;
  int swz = (bid & 7) * (2048 / 8) + (bid >> 3);
  int mb = swz >> 5;         // N/128 = 32 tiles per row
  int nb = swz & 31;
  int brow = mb * 128;
  int bcol = nb * 128;

  int tid  = threadIdx.x;
  int lane = tid & 63;
  int wid  = tid >> 6;
  int wr   = wid >> 1;
  int wc   = wid & 1;

  f32x4 acc[4][4];
#pragma unroll
  for (int m = 0; m < 4; ++m)
#pragma unroll
    for (int n = 0; n < 4; ++n) acc[m][n] = (f32x4)0.0f;

  const char* Abase = (const char*)A + (size_t)brow * (K_DIM * 2);
  const char* Bbase = (const char*)B + (size_t)bcol * (K_DIM * 2);

  // fragment read addresses (bytes) within LDS tile: row stride 64B
  int fragA_row[4], fragB_row[4];
#pragma unroll
  for (int m = 0; m < 4; ++m) fragA_row[m] = (wr * 64 + m * 16 + (lane & 15)) * 32;
#pragma unroll
  for (int n = 0; n < 4; ++n) fragB_row[n] = (wc * 64 + n * 16 + (lane & 15)) * 32;
  int kgrp = (lane >> 4) * 8;   // element offset within row

  for (int k0 = 0; k0 < K_DIM; k0 += 32) {
    // stage A (8KB) + B (8KB): 2 rounds each, 256 lanes x 16B
#pragma unroll
    for (int r = 0; r < 2; ++r) {
      int f    = (r * 256 + tid) * 16;   // byte offset in tile
      int row  = f >> 6;                 // 64B per row
      int colb = f & 63;
      GLD_LDS16(Abase + (size_t)row * (K_DIM * 2) + k0 * 2 + colb, (char*)lsA + f);
    }
#pragma unroll
    for (int r = 0; r < 2; ++r) {
      int f    = (r * 256 + tid) * 16;
      int row  = f >> 6;
      int colb = f & 63;
      GLD_LDS16(Bbase + (size_t)row * (K_DIM * 2) + k0 * 2 + colb, (char*)lsB + f);
    }
    __syncthreads();   // compiler emits s_waitcnt vmcnt(0) before barrier

    bf16x8 a[4], b[4];
#pragma unroll
    for (int m = 0; m < 4; ++m)
      a[m] = *(const bf16x8*)(lsA + fragA_row[m] + kgrp);
#pragma unroll
    for (int n = 0; n < 4; ++n)
      b[n] = *(const bf16x8*)(lsB + fragB_row[n] + kgrp);

#pragma unroll
    for (int m = 0; m < 4; ++m)
#pragma unroll
      for (int n = 0; n < 4; ++n)
        acc[m][n] = __builtin_amdgcn_mfma_f32_16x16x32_bf16(a[m], b[n], acc[m][n], 0, 0, 0);

    __syncthreads();   // protect LDS before next stage
  }

  // epilogue: C/D layout col = lane&15, row = (lane>>4)*4 + j
  int cL = lane & 15;
  int rL = (lane >> 4) * 4;
#pragma unroll
  for (int n = 0; n < 4; ++n) {
    int col = bcol + wc * 64 + n * 16 + cL;
    float bv = bias[col];
#pragma unroll
    for (int m = 0; m < 4; ++m) {
      int row0 = brow + wr * 64 + m * 16 + rL;
#pragma unroll
      for (int j = 0; j < 4; ++j)
        C[(size_t)(row0 + j) * N_DIM + col] = acc[m][n][j] + bv;
    }
  }
}

extern "C" void kernel_launch(void* const* d_in, const int* in_sizes, int n_in,
                              void* d_out, int out_size, void* d_ws, size_t ws_size,
                              hipStream_t stream) {
  const float* x    = (const float*)d_in[0];
  const int*   qw   = (const int*)d_in[1];
  const float* lut  = (const float*)d_in[2];
  const float* bias = (const float*)d_in[3];
  // d_in[4] = w_bits (fixed 4 for this problem)

  // workspace layout: Wb (N x K bf16, 32MB) then Xb (M x K bf16, 64MB)
  __bf16* Wb = (__bf16*)d_ws;
  __bf16* Xb = (__bf16*)((char*)d_ws + (size_t)N_DIM * K_DIM * 2);

  // 1) dequant W -> bf16
  {
    int total = N_DIM * (K_DIM / 32);     // 524288 threads
    anyprec_dequant_kernel<<<total / 256, 256, 0, stream>>>(qw, lut, Wb);
  }
  // 2) convert x -> bf16
  {
    int n8 = (M_DIM * K_DIM) / 8;         // 4194304
    cvt_x_kernel<<<(n8 + 255) / 256, 256, 0, stream>>>(x, Xb, n8);
  }
  // 3) GEMM + bias
  {
    dim3 grid((M_DIM / 128) * (N_DIM / 128));  // 64*32 = 2048
    anyprec_gemm_kernel<<<grid, 256, 0, stream>>>(Xb, Wb, bias, (float*)d_out);
  }
}

// Round 2
// 276.796 us; speedup vs baseline: 1.4048x; 1.4048x over previous
//
#include <hip/hip_runtime.h>
#include <hip/hip_bf16.h>
#include <stdint.h>

#define M_DIM 8192   // 4*2048
#define N_DIM 4096   // OUT_FEATURES
#define K_DIM 4096   // IN_FEATURES
#define KB2   (K_DIM * 2)   // bytes per K-row

typedef __attribute__((ext_vector_type(8))) __bf16 bf16x8;
typedef __attribute__((ext_vector_type(4))) float  f32x4;

#define GLD_LDS16(gaddr, laddr)                                            \
  __builtin_amdgcn_global_load_lds(                                        \
      (const __attribute__((address_space(1))) uint32_t*)(gaddr),          \
      (__attribute__((address_space(3))) uint32_t*)(laddr), 16, 0, 0)

// ---------------------------------------------------------------------------
// Dequant: qweight (8, O, 128) int32 bit-planes + lut (O,16) -> Wb (O,K) bf16
// ---------------------------------------------------------------------------
__global__ __launch_bounds__(256) void anyprec_dequant_kernel(
    const int* __restrict__ q, const float* __restrict__ lut,
    __bf16* __restrict__ Wb) {
  int t = blockIdx.x * 256 + threadIdx.x;   // 0 .. O*128-1
  int o = t >> 7;
  int w = t & 127;
  const int PLANE = N_DIM * (K_DIM / 32);
  int base = o * (K_DIM / 32) + w;
  uint32_t q0 = (uint32_t)q[0 * PLANE + base];
  uint32_t q1 = (uint32_t)q[1 * PLANE + base];
  uint32_t q2 = (uint32_t)q[2 * PLANE + base];
  uint32_t q3 = (uint32_t)q[3 * PLANE + base];
  const float* lrow = lut + o * 16;

  __bf16 vals[32];
#pragma unroll
  for (int i = 0; i < 32; ++i) {
    uint32_t idx = ((q0 >> i) & 1u) | (((q1 >> i) & 1u) << 1) |
                   (((q2 >> i) & 1u) << 2) | (((q3 >> i) & 1u) << 3);
    vals[i] = (__bf16)lrow[idx];
  }
  bf16x8* dst = (bf16x8*)(Wb + (size_t)o * K_DIM + w * 32);
#pragma unroll
  for (int r = 0; r < 4; ++r) {
    bf16x8 v;
#pragma unroll
    for (int j = 0; j < 8; ++j) v[j] = vals[r * 8 + j];
    dst[r] = v;
  }
}

// ---------------------------------------------------------------------------
// x fp32 -> bf16
// ---------------------------------------------------------------------------
__global__ __launch_bounds__(256) void cvt_x_kernel(
    const float* __restrict__ x, __bf16* __restrict__ xb, int n8) {
  int t = blockIdx.x * 256 + threadIdx.x;
  if (t >= n8) return;
  f32x4 a = ((const f32x4*)x)[t * 2];
  f32x4 b = ((const f32x4*)x)[t * 2 + 1];
  bf16x8 v;
  v[0] = (__bf16)a[0]; v[1] = (__bf16)a[1]; v[2] = (__bf16)a[2]; v[3] = (__bf16)a[3];
  v[4] = (__bf16)b[0]; v[5] = (__bf16)b[1]; v[6] = (__bf16)b[2]; v[7] = (__bf16)b[3];
  ((bf16x8*)xb)[t] = v;
}

// ---------------------------------------------------------------------------
// 256x256 8-phase bf16 GEMM: C[M,N] = A[M,K] * B[N,K]^T + bias (fp32 out)
// 512 thr = 8 waves (2M x 4N). BK=64. LDS 128 KiB: [buf][A/B][half][128x64].
// Wave output: rows {qm*128 + wr*64 + 0..63}, cols {qn*128 + wc*32 + 0..31}
// -> each A/B half read in exactly 2 of 4 phases per tile, enabling
// counted vmcnt(4) (never 0) with 1 half-tile staged per phase.
// LDS chunk swizzle: chunk ^= (row&7), applied on global SOURCE address
// (linear global_load_lds dest) and on ds_read address.
// ---------------------------------------------------------------------------
__global__ __launch_bounds__(512, 2) void anyprec_gemm_kernel(
    const __bf16* __restrict__ A,   // M x K bf16
    const __bf16* __restrict__ B,   // N x K bf16
    const float* __restrict__ bias,
    float* __restrict__ C) {
  __shared__ __bf16 lds[2][2][2][128 * 64];   // 131072 B

  // XCD-aware bijective swizzle (512 wgs, 512%8==0)
  int bid = blockIdx.x;
  int swz = (bid & 7) * 64 + (bid >> 3);
  int mb = swz >> 4;    // 32 m-tiles
  int nb = swz & 15;    // 16 n-tiles

  const int tid  = threadIdx.x;
  const int lane = tid & 63;
  const int wid  = tid >> 6;
  const int wr   = wid >> 2;   // 0..1
  const int wc   = wid & 3;    // 0..3

  // staging: thread handles LDS 16B-chunks tid and tid+512 of each half-tile
  const char* gA = (const char*)A + (size_t)mb * 256 * KB2;
  const char* gB = (const char*)B + (size_t)nb * 256 * KB2;
  const size_t gro0 = (size_t)(tid >> 3) * KB2;       // row  = chunk>>3
  const size_t gro1 = gro0 + (size_t)64 * KB2;        // row + 64
  const int    scx  = (((tid & 7) ^ ((tid >> 3) & 7)) << 4);  // swizzled src chunk
  const int    lt0  = tid * 16;
  const int    lt1  = tid * 16 + 8192;

  // ds_read offsets (row&7 == lane&7 for all frags)
  const int aoff0 = (wr * 64 + (lane & 15)) * 128;
  const int boff0 = (wc * 32 + (lane & 15)) * 128;
  const int kko0  = (((lane >> 4)) ^ (lane & 7)) << 4;
  const int kko1  = ((4 + (lane >> 4)) ^ (lane & 7)) << 4;

  f32x4 acc[2][2][4][2];
#pragma unroll
  for (int qm = 0; qm < 2; ++qm)
#pragma unroll
    for (int qn = 0; qn < 2; ++qn)
#pragma unroll
      for (int mf = 0; mf < 4; ++mf)
#pragma unroll
        for (int nf = 0; nf < 2; ++nf) acc[qm][qn][mf][nf] = (f32x4)0.0f;

  bf16x8 a[4][2], b[2][2];

#define STAGE(mat, h, buf, t) {                                            \
    char* lb_ = (char*)&lds[buf][mat][h][0];                               \
    const char* gb_ = (mat ? gB : gA) + (size_t)(h) * 128 * KB2            \
                      + (size_t)(t) * 128;                                 \
    GLD_LDS16(gb_ + gro0 + scx, lb_ + lt0);                                \
    GLD_LDS16(gb_ + gro1 + scx, lb_ + lt1); }

#define LDA(qm, buf) {                                                     \
    const char* p_ = (const char*)&lds[buf][0][qm][0] + aoff0;             \
    _Pragma("unroll")                                                      \
    for (int mf = 0; mf < 4; ++mf) {                                       \
      a[mf][0] = *(const bf16x8*)(p_ + mf * 2048 + kko0);                  \
      a[mf][1] = *(const bf16x8*)(p_ + mf * 2048 + kko1); } }

#define LDB(qn, buf) {                                                     \
    const char* p_ = (const char*)&lds[buf][1][qn][0] + boff0;             \
    _Pragma("unroll")                                                      \
    for (int nf = 0; nf < 2; ++nf) {                                       \
      b[nf][0] = *(const bf16x8*)(p_ + nf * 2048 + kko0);                  \
      b[nf][1] = *(const bf16x8*)(p_ + nf * 2048 + kko1); } }

#define MMA(qm, qn) {                                                      \
    _Pragma("unroll")                                                      \
    for (int mf = 0; mf < 4; ++mf)                                         \
      _Pragma("unroll")                                                    \
      for (int nf = 0; nf < 2; ++nf) {                                     \
        acc[qm][qn][mf][nf] = __builtin_amdgcn_mfma_f32_16x16x32_bf16(     \
            a[mf][0], b[nf][0], acc[qm][qn][mf][nf], 0, 0, 0);             \
        acc[qm][qn][mf][nf] = __builtin_amdgcn_mfma_f32_16x16x32_bf16(     \
            a[mf][1], b[nf][1], acc[qm][qn][mf][nf], 0, 0, 0); } }

#define SYNC_PRE {                                                         \
    __builtin_amdgcn_s_barrier();                                          \
    asm volatile("s_waitcnt lgkmcnt(0)" ::: "memory");                     \
    __builtin_amdgcn_sched_barrier(0);                                     \
    __builtin_amdgcn_s_setprio(1); }

#define SYNC_POST {                                                        \
    __builtin_amdgcn_s_setprio(0);                                         \
    __builtin_amdgcn_sched_barrier(0);                                     \
    __builtin_amdgcn_s_barrier(); }

#define SYNC_POST_V4 {                                                     \
    __builtin_amdgcn_s_setprio(0);                                         \
    __builtin_amdgcn_sched_barrier(0);                                     \
    asm volatile("s_waitcnt vmcnt(4)" ::: "memory");                       \
    __builtin_amdgcn_s_barrier(); }

  // ---- prologue: tile0 fully + A0(1), B1(1); drain tile0, keep 4 in flight
  STAGE(0, 0, 0, 0);  // A0(0)
  STAGE(1, 0, 0, 0);  // B0(0)
  STAGE(1, 1, 0, 0);  // B1(0)
  STAGE(0, 1, 0, 0);  // A1(0)
  STAGE(0, 0, 1, 1);  // A0(1)
  STAGE(1, 1, 1, 1);  // B1(1)
  asm volatile("s_waitcnt vmcnt(4)" ::: "memory");
  __builtin_amdgcn_s_barrier();

  // ---- main loop: tiles 2i (buf0) and 2i+1 (buf1), i = 0..30
  for (int i = 0; i < 31; ++i) {
    const int t1 = 2 * i + 1, t2 = 2 * i + 2, t3 = 2 * i + 3;
    // ph1: quad (A0,B0) of even tile
    LDA(0, 0); LDB(0, 0); STAGE(0, 1, 1, t1);   // A1(t1)
    SYNC_PRE; MMA(0, 0); SYNC_POST;
    // ph2: quad (A0,B1)
    LDB(1, 0); STAGE(1, 0, 1, t1);              // B0(t1)
    SYNC_PRE; MMA(0, 1); SYNC_POST;
    // ph3: quad (A1,B1)
    LDA(1, 0); STAGE(0, 0, 0, t2);              // A0(t2)
    SYNC_PRE; MMA(1, 1); SYNC_POST;
    // ph4: quad (A1,B0)  (B0 re-read)
    LDB(0, 0); STAGE(1, 1, 0, t2);              // B1(t2)
    SYNC_PRE; MMA(1, 0); SYNC_POST_V4;          // odd tile now resident
    // ph5: quad (A0,B0) of odd tile
    LDA(0, 1); LDB(0, 1); STAGE(0, 1, 0, t2);   // A1(t2)
    SYNC_PRE; MMA(0, 0); SYNC_POST;
    // ph6
    LDB(1, 1); STAGE(1, 0, 0, t2);              // B0(t2)
    SYNC_PRE; MMA(0, 1); SYNC_POST;
    // ph7
    LDA(1, 1); STAGE(0, 0, 1, t3);              // A0(t3)
    SYNC_PRE; MMA(1, 1); SYNC_POST;
    // ph8
    LDB(0, 1); STAGE(1, 1, 1, t3);              // B1(t3)
    SYNC_PRE; MMA(1, 0); SYNC_POST_V4;          // next even tile resident
  }

  // ---- tail: tiles 62 (buf0), 63 (buf1)
  LDA(0, 0); LDB(0, 0); STAGE(0, 1, 1, 63);     // A1(63)
  SYNC_PRE; MMA(0, 0); SYNC_POST;
  LDB(1, 0); STAGE(1, 0, 1, 63);                // B0(63)
  SYNC_PRE; MMA(0, 1); SYNC_POST;
  LDA(1, 0);
  SYNC_PRE; MMA(1, 1); SYNC_POST;
  LDB(0, 0);
  SYNC_PRE; MMA(1, 0);
  __builtin_amdgcn_s_setprio(0);
  __builtin_amdgcn_sched_barrier(0);
  asm volatile("s_waitcnt vmcnt(0)" ::: "memory");
  __builtin_amdgcn_s_barrier();
  LDA(0, 1); LDB(0, 1); MMA(0, 0);
  LDB(1, 1); MMA(0, 1);
  LDA(1, 1); MMA(1, 1);
  LDB(0, 1); MMA(1, 0);

  // ---- epilogue: C/D layout col=lane&15, row=(lane>>4)*4+j
  const int cL = lane & 15;
  const int rL = (lane >> 4) * 4;
#pragma unroll
  for (int qn = 0; qn < 2; ++qn)
#pragma unroll
    for (int nf = 0; nf < 2; ++nf) {
      int col = nb * 256 + qn * 128 + wc * 32 + nf * 16 + cL;
      float bv = bias[col];
#pragma unroll
      for (int qm = 0; qm < 2; ++qm)
#pragma unroll
        for (int mf = 0; mf < 4; ++mf) {
          int row0 = mb * 256 + qm * 128 + wr * 64 + mf * 16 + rL;
#pragma unroll
          for (int j = 0; j < 4; ++j)
            C[(size_t)(row0 + j) * N_DIM + col] = acc[qm][qn][mf][nf][j] + bv;
        }
    }
#undef STAGE
#undef LDA
#undef LDB
#undef MMA
#undef SYNC_PRE
#undef SYNC_POST
#undef SYNC_POST_V4
}

extern "C" void kernel_launch(void* const* d_in, const int* in_sizes, int n_in,
                              void* d_out, int out_size, void* d_ws, size_t ws_size,
                              hipStream_t stream) {
  const float* x    = (const float*)d_in[0];
  const int*   qw   = (const int*)d_in[1];
  const float* lut  = (const float*)d_in[2];
  const float* bias = (const float*)d_in[3];

  __bf16* Wb = (__bf16*)d_ws;
  __bf16* Xb = (__bf16*)((char*)d_ws + (size_t)N_DIM * K_DIM * 2);

  {
    int total = N_DIM * (K_DIM / 32);
    anyprec_dequant_kernel<<<total / 256, 256, 0, stream>>>(qw, lut, Wb);
  }
  {
    int n8 = (M_DIM * K_DIM) / 8;
    cvt_x_kernel<<<(n8 + 255) / 256, 256, 0, stream>>>(x, Xb, n8);
  }
  {
    dim3 grid((M_DIM / 256) * (N_DIM / 256));  // 32*16 = 512
    anyprec_gemm_kernel<<<grid, 512, 0, stream>>>(Xb, Wb, bias, (float*)d_out);
  }
}